// Round 1
// baseline (206.473 us; speedup 1.0000x reference)
//
#include <hip/hip_runtime.h>

// PartChamferLoss: src/dst [B=16, K=8, 3, 1024] f32 -> scalar f32.
// out = (1/(BK*M)) * sum_{b,k,m} sqrt(min_n d2) + (1/(BK*N)) * sum_{b,k,n} sqrt(min_m d2)
// One direction-agnostic kernel, called twice with swapped pointers.

#define NPTS 1024
#define BLOCK 256
#define STRIPES (NPTS / BLOCK)  // 4 blocks per (b,k) pair per direction

__global__ __launch_bounds__(BLOCK) void chamfer_dir_kernel(
    const float* __restrict__ A,   // query points  [BK, 3, NPTS]
    const float* __restrict__ Bp,  // target points [BK, 3, NPTS]
    float* __restrict__ out, float scale) {
  __shared__ float4 tgt[NPTS];     // x, y, z, x^2+y^2+z^2  (16 KB)

  const int bk = blockIdx.x / STRIPES;
  const int stripe = blockIdx.x % STRIPES;
  const float* Ab = A + (size_t)bk * 3 * NPTS;
  const float* Bb = Bp + (size_t)bk * 3 * NPTS;
  const int tid = threadIdx.x;

  // Stage targets into LDS (coalesced global reads).
  for (int n = tid; n < NPTS; n += BLOCK) {
    float x = Bb[n];
    float y = Bb[NPTS + n];
    float z = Bb[2 * NPTS + n];
    tgt[n] = make_float4(x, y, z, fmaf(x, x, fmaf(y, y, z * z)));
  }
  __syncthreads();

  // Each thread owns one query point.
  const int m = stripe * BLOCK + tid;
  const float xs = Ab[m];
  const float ys = Ab[NPTS + m];
  const float zs = Ab[2 * NPTS + m];
  const float ca = -2.0f * xs, cb = -2.0f * ys, cc = -2.0f * zs;
  const float sbase = fmaf(xs, xs, fmaf(ys, ys, zs * zs));

  float mn = 3.4e38f;
#pragma unroll 8
  for (int n = 0; n < NPTS; ++n) {
    float4 d = tgt[n];  // uniform address across the wave -> LDS broadcast
    float t = sbase + d.w;
    t = fmaf(cc, d.z, t);
    t = fmaf(cb, d.y, t);
    t = fmaf(ca, d.x, t);
    mn = fminf(mn, t);
  }
  float v = sqrtf(fmaxf(mn, 0.0f));  // sqrt hoisted out of the min loop

  // Wave64 reduce, then cross-wave via LDS.
  for (int off = 32; off > 0; off >>= 1) v += __shfl_down(v, off);
  __shared__ float wsum[BLOCK / 64];
  if ((tid & 63) == 0) wsum[tid >> 6] = v;
  __syncthreads();
  if (tid == 0) {
    float s = 0.0f;
#pragma unroll
    for (int w = 0; w < BLOCK / 64; ++w) s += wsum[w];
    atomicAdd(out, s * scale);
  }
}

extern "C" void kernel_launch(void* const* d_in, const int* in_sizes, int n_in,
                              void* d_out, int out_size, void* d_ws, size_t ws_size,
                              hipStream_t stream) {
  const float* src = (const float*)d_in[0];  // [B,K,3,M]
  const float* dst = (const float*)d_in[1];  // [B,K,3,N]
  float* out = (float*)d_out;                // scalar f32

  const int BK = in_sizes[0] / (3 * NPTS);   // 16*8 = 128
  const float scale = 1.0f / (float)(BK * NPTS);  // 1/(K*B*M), M==N

  // d_out is re-poisoned to 0xAA before every timed launch — zero it.
  hipMemsetAsync(out, 0, sizeof(float), stream);

  dim3 grid(BK * STRIPES);
  // forward: min over dst for each src point
  chamfer_dir_kernel<<<grid, BLOCK, 0, stream>>>(src, dst, out, scale);
  // backward: min over src for each dst point
  chamfer_dir_kernel<<<grid, BLOCK, 0, stream>>>(dst, src, out, scale);
}

// Round 2
// 88.606 us; speedup vs baseline: 2.3303x; 2.3303x over previous
//
#include <hip/hip_runtime.h>

// PartChamferLoss: src/dst [B=16, K=8, 3, 1024] f32 -> scalar f32.
// out = (1/(BK*M)) * sum_{b,k,m} sqrt(min_n d2) + (1/(BK*N)) * sum_{b,k,n} sqrt(min_m d2)
// Fused single launch: grid = bk(128) x dir(2) x query-half(2) = 512 blocks.
// Each thread owns Q=2 query points -> 1 LDS read feeds 10 VALU ops.

#define NPTS 1024
#define BLOCK 256

__global__ __launch_bounds__(BLOCK) void chamfer_fused_kernel(
    const float* __restrict__ src,  // [BK, 3, NPTS]
    const float* __restrict__ dst,  // [BK, 3, NPTS]
    float* __restrict__ out, float scale) {
  __shared__ float4 tgt[NPTS];  // x, y, z, x^2+y^2+z^2  (16 KB)

  const int task = blockIdx.x;
  const int h = task & 1;            // query half
  const int dir = (task >> 1) & 1;   // 0: src->dst, 1: dst->src
  const int bk = task >> 2;          // 0..127

  const float* A = (dir ? dst : src) + (size_t)bk * 3 * NPTS;  // queries
  const float* Bb = (dir ? src : dst) + (size_t)bk * 3 * NPTS; // targets
  const int tid = threadIdx.x;

  // Stage all 1024 targets into LDS (coalesced).
  for (int n = tid; n < NPTS; n += BLOCK) {
    float x = Bb[n];
    float y = Bb[NPTS + n];
    float z = Bb[2 * NPTS + n];
    tgt[n] = make_float4(x, y, z, fmaf(x, x, fmaf(y, y, z * z)));
  }
  __syncthreads();

  // Two query points per thread.
  const int m0 = h * 512 + tid;
  const int m1 = m0 + 256;
  const float x0 = A[m0], y0 = A[NPTS + m0], z0 = A[2 * NPTS + m0];
  const float x1 = A[m1], y1 = A[NPTS + m1], z1 = A[2 * NPTS + m1];
  const float a0 = -2.0f * x0, b0 = -2.0f * y0, c0 = -2.0f * z0;
  const float a1 = -2.0f * x1, b1 = -2.0f * y1, c1 = -2.0f * z1;
  const float s0 = fmaf(x0, x0, fmaf(y0, y0, z0 * z0));
  const float s1 = fmaf(x1, x1, fmaf(y1, y1, z1 * z1));

  float mn0 = 3.4e38f, mn1 = 3.4e38f;
#pragma unroll 8
  for (int n = 0; n < NPTS; ++n) {
    float4 d = tgt[n];  // wave-uniform address -> LDS broadcast, no conflict
    float t0 = s0 + d.w;
    float t1 = s1 + d.w;
    t0 = fmaf(c0, d.z, t0);
    t1 = fmaf(c1, d.z, t1);
    t0 = fmaf(b0, d.y, t0);
    t1 = fmaf(b1, d.y, t1);
    t0 = fmaf(a0, d.x, t0);
    t1 = fmaf(a1, d.x, t1);
    mn0 = fminf(mn0, t0);
    mn1 = fminf(mn1, t1);
  }
  // sqrt hoisted out of the min loop (monotone)
  float v = sqrtf(fmaxf(mn0, 0.0f)) + sqrtf(fmaxf(mn1, 0.0f));

  // Wave64 reduce, then cross-wave via LDS, one atomic per block.
  for (int off = 32; off > 0; off >>= 1) v += __shfl_down(v, off);
  __shared__ float wsum[BLOCK / 64];
  if ((tid & 63) == 0) wsum[tid >> 6] = v;
  __syncthreads();
  if (tid == 0) {
    float s = 0.0f;
#pragma unroll
    for (int w = 0; w < BLOCK / 64; ++w) s += wsum[w];
    atomicAdd(out, s * scale);
  }
}

extern "C" void kernel_launch(void* const* d_in, const int* in_sizes, int n_in,
                              void* d_out, int out_size, void* d_ws, size_t ws_size,
                              hipStream_t stream) {
  const float* src = (const float*)d_in[0];  // [B,K,3,M]
  const float* dst = (const float*)d_in[1];  // [B,K,3,N]
  float* out = (float*)d_out;                // scalar f32

  const int BK = in_sizes[0] / (3 * NPTS);        // 16*8 = 128
  const float scale = 1.0f / (float)(BK * NPTS);  // 1/(B*K*M), M==N

  // d_out is re-poisoned to 0xAA before every timed launch — zero it.
  hipMemsetAsync(out, 0, sizeof(float), stream);

  dim3 grid(BK * 2 * 2);  // bk x dir x query-half = 512
  chamfer_fused_kernel<<<grid, BLOCK, 0, stream>>>(src, dst, out, scale);
}